// Round 7
// baseline (266.422 us; speedup 1.0000x reference)
//
#include <hip/hip_runtime.h>

#define BS 256
#define HS 512
#define IN_DIM 64
#define OUT_DIM 4

typedef float nfloat4 __attribute__((ext_vector_type(4)));  // native vec for nt builtins

// ---------------------------------------------------------------------------
// Fused v2: one 1024-thread workgroup per batch element b.
// Traffic-optimal (hebb fetched from HBM once, 271 MB + 268 MB write, proven
// by R6 FETCH_SIZE); this version fixes the memory-level-parallelism deficit:
//   Phase A: 8 independent row-accumulators per wave -> 48 loads in flight
//            before the (mutually independent) shfl reduce chains.
//   Phase C: invariant LDS reads hoisted + unrolled streaming loop.
// ---------------------------------------------------------------------------
__global__ __launch_bounds__(1024) void fused_kernel(
    const float* __restrict__ inputs,
    const float* __restrict__ hidden,
    const float* __restrict__ hebb,
    const float* __restrict__ Wi,  const float* __restrict__ bi,
    const float* __restrict__ w,   const float* __restrict__ alpha,
    const float* __restrict__ Wo,  const float* __restrict__ bo,
    const float* __restrict__ Wv,  const float* __restrict__ bv,
    const float* __restrict__ Wda, const float* __restrict__ bda,
    float* __restrict__ activout, float* __restrict__ valueout,
    float* __restrict__ daout,    float* __restrict__ hactiv,
    float* __restrict__ hebb_new)
{
    const int b    = blockIdx.x;
    const int tid  = threadIdx.x;
    const int wave = tid >> 6;
    const int lane = tid & 63;

    __shared__ __align__(16) float sh_hidden[HS];
    __shared__ __align__(16) float sh_in[IN_DIM];
    __shared__ float sh_rec[HS];
    __shared__ float sh_scale[HS];
    __shared__ float red[16][6];
    __shared__ float da_sh;

    // stage hidden[b,:] and inputs[b,:] into LDS
    if (tid < HS / 4)
        ((float4*)sh_hidden)[tid] = ((const float4*)(hidden + (size_t)b * HS))[tid];
    if (tid >= 512 && tid < 512 + IN_DIM / 4)
        ((float4*)sh_in)[tid - 512] = ((const float4*)(inputs + (size_t)b * IN_DIM))[tid - 512];
    __syncthreads();

    // hidden fragment this lane uses — invariant across all rows (phases A & C)
    const float4 hh0 = ((const float4*)sh_hidden)[lane];
    const float4 hh1 = ((const float4*)sh_hidden)[lane + 64];

    // ---------------- Phase A: rec ----------------
    const float4* __restrict__ hebb4b = (const float4*)(hebb + (size_t)b * HS * HS);
    const float4* __restrict__ w4a    = (const float4*)w;
    const float4* __restrict__ a4a    = (const float4*)alpha;

    for (int rb = 0; rb < 32; rb += 8) {
        float sum[8];
#pragma unroll
        for (int rr = 0; rr < 8; ++rr) sum[rr] = 0.f;
#pragma unroll
        for (int rr = 0; rr < 8; ++rr) {
            const int i = wave * 32 + rb + rr;
            const int base = i * (HS / 4);
            {
                const float4 hb = hebb4b[base + lane];
                const float4 ww = w4a[base + lane];
                const float4 aa = a4a[base + lane];
                sum[rr] += hh0.x * (ww.x + aa.x * hb.x);
                sum[rr] += hh0.y * (ww.y + aa.y * hb.y);
                sum[rr] += hh0.z * (ww.z + aa.z * hb.z);
                sum[rr] += hh0.w * (ww.w + aa.w * hb.w);
            }
            {
                const float4 hb = hebb4b[base + lane + 64];
                const float4 ww = w4a[base + lane + 64];
                const float4 aa = a4a[base + lane + 64];
                sum[rr] += hh1.x * (ww.x + aa.x * hb.x);
                sum[rr] += hh1.y * (ww.y + aa.y * hb.y);
                sum[rr] += hh1.z * (ww.z + aa.z * hb.z);
                sum[rr] += hh1.w * (ww.w + aa.w * hb.w);
            }
        }
        // 8 independent reduce chains — they pipeline against each other
#pragma unroll
        for (int off = 32; off > 0; off >>= 1) {
#pragma unroll
            for (int rr = 0; rr < 8; ++rr)
                sum[rr] += __shfl_xor(sum[rr], off, 64);
        }
        if (lane == 0) {
#pragma unroll
            for (int rr = 0; rr < 8; ++rr)
                sh_rec[wave * 32 + rb + rr] = sum[rr];
        }
    }
    __syncthreads();

    // ---------------- Phase B: activations + heads ----------------
    float h = 0.f;
    float p[6] = {0.f, 0.f, 0.f, 0.f, 0.f, 0.f};
    if (tid < HS) {
        float dot = 0.f;
        const float4* __restrict__ wi4 = (const float4*)(Wi + (size_t)tid * IN_DIM);
#pragma unroll
        for (int t = 0; t < IN_DIM / 4; ++t) {
            const float4 a = wi4[t];
            const float4 x = ((const float4*)sh_in)[t];
            dot += a.x * x.x + a.y * x.y + a.z * x.z + a.w * x.w;
        }
        h = tanhf(dot + bi[tid] + sh_rec[tid]);
        hactiv[(size_t)b * HS + tid] = h;
        p[0] = h * Wo[0 * HS + tid];
        p[1] = h * Wo[1 * HS + tid];
        p[2] = h * Wo[2 * HS + tid];
        p[3] = h * Wo[3 * HS + tid];
        p[4] = h * Wv[tid];
        p[5] = h * Wda[tid];
    }
#pragma unroll
    for (int k = 0; k < 6; ++k) {
        float s = p[k];
#pragma unroll
        for (int off = 32; off > 0; off >>= 1)
            s += __shfl_xor(s, off, 64);
        if (lane == 0) red[wave][k] = s;
    }
    __syncthreads();

    if (tid < 6) {
        float s = 0.f;
#pragma unroll
        for (int wv = 0; wv < 16; ++wv) s += red[wv][tid];
        if (tid < 4) {
            activout[b * OUT_DIM + tid] = s + bo[tid];
        } else if (tid == 4) {
            valueout[b] = s + bv[0];
        } else {
            const float da = tanhf(s + bda[0]);
            daout[b] = da;
            da_sh = da;
        }
    }
    __syncthreads();

    if (tid < HS) sh_scale[tid] = da_sh * h;
    __syncthreads();

    // ---------------- Phase C: hebb update ----------------
    nfloat4* __restrict__ dst = (nfloat4*)(hebb_new + (size_t)b * HS * HS);
#pragma unroll 4
    for (int r = 0; r < 32; ++r) {
        const int i = wave * 32 + r;
        const float s = sh_scale[i];
        const int base = i * (HS / 4);
        {
            const float4 hb = hebb4b[base + lane];
            nfloat4 o;
            o.x = fminf(fmaxf(hb.x + s * hh0.x, -1.f), 1.f);
            o.y = fminf(fmaxf(hb.y + s * hh0.y, -1.f), 1.f);
            o.z = fminf(fmaxf(hb.z + s * hh0.z, -1.f), 1.f);
            o.w = fminf(fmaxf(hb.w + s * hh0.w, -1.f), 1.f);
            __builtin_nontemporal_store(o, dst + base + lane);
        }
        {
            const float4 hb = hebb4b[base + lane + 64];
            nfloat4 o;
            o.x = fminf(fmaxf(hb.x + s * hh1.x, -1.f), 1.f);
            o.y = fminf(fmaxf(hb.y + s * hh1.y, -1.f), 1.f);
            o.z = fminf(fmaxf(hb.z + s * hh1.z, -1.f), 1.f);
            o.w = fminf(fmaxf(hb.w + s * hh1.w, -1.f), 1.f);
            __builtin_nontemporal_store(o, dst + base + lane + 64);
        }
    }
}

extern "C" void kernel_launch(void* const* d_in, const int* in_sizes, int n_in,
                              void* d_out, int out_size, void* d_ws, size_t ws_size,
                              hipStream_t stream) {
    const float* inputs = (const float*)d_in[0];
    const float* hidden = (const float*)d_in[1];
    const float* hebb   = (const float*)d_in[2];
    const float* Wi     = (const float*)d_in[3];
    const float* bi     = (const float*)d_in[4];
    const float* w      = (const float*)d_in[5];
    const float* alpha  = (const float*)d_in[6];
    const float* Wo     = (const float*)d_in[7];
    const float* bo     = (const float*)d_in[8];
    const float* Wv     = (const float*)d_in[9];
    const float* bv     = (const float*)d_in[10];
    const float* Wda    = (const float*)d_in[11];
    const float* bda    = (const float*)d_in[12];

    float* out = (float*)d_out;
    float* activout = out;                       // [256,4]   = 1024
    float* valueout = out + 1024;                // [256,1]   = 256
    float* daout    = out + 1280;                // [256,1]   = 256
    float* hactiv   = out + 1536;                // [256,512] = 131072
    float* hebb_new = out + 1536 + BS * HS;      // [256,512,512]

    fused_kernel<<<BS, 1024, 0, stream>>>(inputs, hidden, hebb, Wi, bi, w, alpha,
                                          Wo, bo, Wv, bv, Wda, bda,
                                          activout, valueout, daout, hactiv,
                                          hebb_new);
}

// Round 8
// 137.310 us; speedup vs baseline: 1.9403x; 1.9403x over previous
//
#include <hip/hip_runtime.h>

#define BS 256
#define HS 512
#define IN_DIM 64
#define OUT_DIM 4

typedef float nfloat4 __attribute__((ext_vector_type(4)));  // native vec for nt builtins

// ---------------------------------------------------------------------------
// Kernel 1: rec[b,i] = sum_j hidden[b,j] * (w[i,j] + alpha[i,j]*hebb[b,i,j])
// Each wave handles TWO consecutive rows (same b): 12 independent float4
// loads in flight, two interleaved shfl-reduce chains. Flat grid keeps the
// streaming order cache-friendly (forward pass leaves hebb tail in L3).
// ---------------------------------------------------------------------------
__global__ __launch_bounds__(256) void rec_kernel(
    const float* __restrict__ hidden,
    const float* __restrict__ hebb,
    const float* __restrict__ w,
    const float* __restrict__ alpha,
    float* __restrict__ rec)
{
    const int wid  = blockIdx.x * 4 + (threadIdx.x >> 6);   // wave id
    const int lane = threadIdx.x & 63;
    const int row0 = wid * 2;                // two consecutive rows, same b
    const int b  = row0 >> 9;
    const int i0 = row0 & (HS - 1);

    const float4* __restrict__ hebb40 = (const float4*)(hebb + (size_t)row0 * HS);
    const float4* __restrict__ hebb41 = hebb40 + HS / 4;
    const float4* __restrict__ w40    = (const float4*)(w     + (size_t)i0 * HS);
    const float4* __restrict__ w41    = w40 + HS / 4;
    const float4* __restrict__ a40    = (const float4*)(alpha + (size_t)i0 * HS);
    const float4* __restrict__ a41    = a40 + HS / 4;
    const float4* __restrict__ h4     = (const float4*)(hidden + (size_t)b * HS);

    const float4 hh0 = h4[lane];
    const float4 hh1 = h4[lane + 64];

    // issue all 12 loads before consuming
    const float4 hbA0 = hebb40[lane];
    const float4 hbA1 = hebb40[lane + 64];
    const float4 hbB0 = hebb41[lane];
    const float4 hbB1 = hebb41[lane + 64];
    const float4 wwA0 = w40[lane];
    const float4 wwA1 = w40[lane + 64];
    const float4 wwB0 = w41[lane];
    const float4 wwB1 = w41[lane + 64];
    const float4 aaA0 = a40[lane];
    const float4 aaA1 = a40[lane + 64];
    const float4 aaB0 = a41[lane];
    const float4 aaB1 = a41[lane + 64];

    float sA = 0.f, sB = 0.f;
    sA += hh0.x * (wwA0.x + aaA0.x * hbA0.x);
    sA += hh0.y * (wwA0.y + aaA0.y * hbA0.y);
    sA += hh0.z * (wwA0.z + aaA0.z * hbA0.z);
    sA += hh0.w * (wwA0.w + aaA0.w * hbA0.w);
    sA += hh1.x * (wwA1.x + aaA1.x * hbA1.x);
    sA += hh1.y * (wwA1.y + aaA1.y * hbA1.y);
    sA += hh1.z * (wwA1.z + aaA1.z * hbA1.z);
    sA += hh1.w * (wwA1.w + aaA1.w * hbA1.w);

    sB += hh0.x * (wwB0.x + aaB0.x * hbB0.x);
    sB += hh0.y * (wwB0.y + aaB0.y * hbB0.y);
    sB += hh0.z * (wwB0.z + aaB0.z * hbB0.z);
    sB += hh0.w * (wwB0.w + aaB0.w * hbB0.w);
    sB += hh1.x * (wwB1.x + aaB1.x * hbB1.x);
    sB += hh1.y * (wwB1.y + aaB1.y * hbB1.y);
    sB += hh1.z * (wwB1.z + aaB1.z * hbB1.z);
    sB += hh1.w * (wwB1.w + aaB1.w * hbB1.w);

    // two independent reduce chains, interleaved
#pragma unroll
    for (int off = 32; off > 0; off >>= 1) {
        sA += __shfl_xor(sA, off, 64);
        sB += __shfl_xor(sB, off, 64);
    }
    if (lane == 0) {
        rec[row0]     = sA;
        rec[row0 + 1] = sB;
    }
}

// ---------------------------------------------------------------------------
// Kernel 2: per batch element b (one block of 512 threads, thread i = unit i):
//   hactiv[b,i] = tanh(inputs[b,:]@Wi[i,:] + bi[i] + rec[b,i])
//   activout[b,:], valueout[b], DAout[b] via block reductions
//   scale[b,i] = DAout[b] * hactiv[b,i]
// ---------------------------------------------------------------------------
__global__ __launch_bounds__(512) void act_kernel(
    const float* __restrict__ inputs,
    const float* __restrict__ Wi, const float* __restrict__ bi,
    const float* __restrict__ rec,
    const float* __restrict__ Wo, const float* __restrict__ bo,
    const float* __restrict__ Wv, const float* __restrict__ bv,
    const float* __restrict__ Wda, const float* __restrict__ bda,
    float* __restrict__ activout, float* __restrict__ valueout,
    float* __restrict__ daout, float* __restrict__ hactiv,
    float* __restrict__ scale)
{
    const int b = blockIdx.x;
    const int i = threadIdx.x;

    __shared__ __align__(16) float sh_in[IN_DIM];
    __shared__ float red[8][8];
    __shared__ float da_sh;

    if (i < IN_DIM) sh_in[i] = inputs[b * IN_DIM + i];
    __syncthreads();

    float dot = 0.f;
    const float4* __restrict__ wi4 = (const float4*)(Wi + (size_t)i * IN_DIM);
    const float4* __restrict__ in4 = (const float4*)sh_in;
#pragma unroll
    for (int t = 0; t < IN_DIM / 4; ++t) {
        const float4 a = wi4[t];
        const float4 x = in4[t];
        dot += a.x * x.x + a.y * x.y + a.z * x.z + a.w * x.w;
    }

    const float h = tanhf(dot + bi[i] + rec[(size_t)b * HS + i]);
    hactiv[(size_t)b * HS + i] = h;

    float p[6];
    p[0] = h * Wo[0 * HS + i];
    p[1] = h * Wo[1 * HS + i];
    p[2] = h * Wo[2 * HS + i];
    p[3] = h * Wo[3 * HS + i];
    p[4] = h * Wv[i];
    p[5] = h * Wda[i];

    const int lane = i & 63, wave = i >> 6;
#pragma unroll
    for (int k = 0; k < 6; ++k) {
        float s = p[k];
#pragma unroll
        for (int off = 32; off > 0; off >>= 1)
            s += __shfl_xor(s, off, 64);
        if (lane == 0) red[wave][k] = s;
    }
    __syncthreads();

    if (i < 6) {
        float s = 0.f;
#pragma unroll
        for (int wv = 0; wv < 8; ++wv) s += red[wv][i];
        if (i < 4) {
            activout[b * OUT_DIM + i] = s + bo[i];
        } else if (i == 4) {
            valueout[b] = s + bv[0];
        } else {
            const float da = tanhf(s + bda[0]);
            daout[b] = da;
            da_sh = da;
        }
    }
    __syncthreads();

    scale[(size_t)b * HS + i] = da_sh * h;
}

// ---------------------------------------------------------------------------
// Kernel 3: hebb_new[b,i,j] = clip(hebb[b,i,j] + scale[b,i]*hidden[b,j], -1, 1)
// Reverse-order streaming (hebb tail is L3-resident after k1's forward pass),
// nt stores (no L3 pollution), 2x unrolled with both loads issued first.
// 4096 blocks x 256 threads -> exactly 16 float4s per thread, no tail.
// ---------------------------------------------------------------------------
__global__ __launch_bounds__(256) void hebb_kernel(
    const float* __restrict__ hebb,
    const float* __restrict__ hidden,
    const float* __restrict__ scale,
    float* __restrict__ hebb_new)
{
    const long long total4 = (long long)BS * HS * HS / 4;    // 16,777,216
    const long long stride = (long long)gridDim.x * blockDim.x; // 1,048,576
    const long long tid    = (long long)blockIdx.x * blockDim.x + threadIdx.x;

#pragma unroll
    for (int k = 0; k < 16; k += 2) {
        const long long vA = total4 - 1 - tid - (long long)k * stride;
        const long long vB = vA - stride;

        const long long eA = vA * 4;
        const int bA = (int)(eA >> 18);
        const int iA = (int)(eA >> 9) & (HS - 1);
        const int jA = (int)eA & (HS - 1);
        const long long eB = vB * 4;
        const int bB = (int)(eB >> 18);
        const int iB = (int)(eB >> 9) & (HS - 1);
        const int jB = (int)eB & (HS - 1);

        // issue both hebb loads before any compute/store
        const float4 hbA = ((const float4*)hebb)[vA];
        const float4 hbB = ((const float4*)hebb)[vB];
        const float  sAs = scale[bA * HS + iA];
        const float4 hiA = *(const float4*)(hidden + bA * HS + jA);
        const float  sBs = scale[bB * HS + iB];
        const float4 hiB = *(const float4*)(hidden + bB * HS + jB);

        nfloat4 oA, oB;
        oA.x = fminf(fmaxf(hbA.x + sAs * hiA.x, -1.f), 1.f);
        oA.y = fminf(fmaxf(hbA.y + sAs * hiA.y, -1.f), 1.f);
        oA.z = fminf(fmaxf(hbA.z + sAs * hiA.z, -1.f), 1.f);
        oA.w = fminf(fmaxf(hbA.w + sAs * hiA.w, -1.f), 1.f);
        oB.x = fminf(fmaxf(hbB.x + sBs * hiB.x, -1.f), 1.f);
        oB.y = fminf(fmaxf(hbB.y + sBs * hiB.y, -1.f), 1.f);
        oB.z = fminf(fmaxf(hbB.z + sBs * hiB.z, -1.f), 1.f);
        oB.w = fminf(fmaxf(hbB.w + sBs * hiB.w, -1.f), 1.f);
        __builtin_nontemporal_store(oA, (nfloat4*)hebb_new + vA);
        __builtin_nontemporal_store(oB, (nfloat4*)hebb_new + vB);
    }
}

extern "C" void kernel_launch(void* const* d_in, const int* in_sizes, int n_in,
                              void* d_out, int out_size, void* d_ws, size_t ws_size,
                              hipStream_t stream) {
    const float* inputs = (const float*)d_in[0];
    const float* hidden = (const float*)d_in[1];
    const float* hebb   = (const float*)d_in[2];
    const float* Wi     = (const float*)d_in[3];
    const float* bi     = (const float*)d_in[4];
    const float* w      = (const float*)d_in[5];
    const float* alpha  = (const float*)d_in[6];
    const float* Wo     = (const float*)d_in[7];
    const float* bo     = (const float*)d_in[8];
    const float* Wv     = (const float*)d_in[9];
    const float* bv     = (const float*)d_in[10];
    const float* Wda    = (const float*)d_in[11];
    const float* bda    = (const float*)d_in[12];

    float* out = (float*)d_out;
    float* activout = out;                       // [256,4]   = 1024
    float* valueout = out + 1024;                // [256,1]   = 256
    float* daout    = out + 1280;                // [256,1]   = 256
    float* hactiv   = out + 1536;                // [256,512] = 131072
    float* hebb_new = out + 1536 + BS * HS;      // [256,512,512]

    float* rec   = (float*)d_ws;
    float* scale = rec;   // same buffer: rec consumed before scale written

    // Kernel 1: 131072 rows, 2 rows/wave, 4 waves/block -> 16384 blocks
    rec_kernel<<<(BS * HS) / 8, 256, 0, stream>>>(hidden, hebb, w, alpha, rec);

    // Kernel 2: one block per batch element
    act_kernel<<<BS, HS, 0, stream>>>(inputs, Wi, bi, rec, Wo, bo, Wv, bv,
                                      Wda, bda, activout, valueout, daout,
                                      hactiv, scale);

    // Kernel 3: reverse streaming update, 4096 blocks
    hebb_kernel<<<4096, 256, 0, stream>>>(hebb, hidden, scale, hebb_new);
}